// Round 3
// baseline (129.854 us; speedup 1.0000x reference)
//
#include <hip/hip_runtime.h>
#include <math.h>

#define D 128
#define K 1024

typedef __attribute__((ext_vector_type(8))) short bf16x8;
typedef __attribute__((ext_vector_type(4))) float f32x4;
typedef unsigned short u16;

// ws layout: [0,4096) hist | [4096,4100) loss | [8192,12288) cnorm | [16384,16384+512K) frag image

__device__ __forceinline__ u16 f2bf(float x) {
    union { float f; unsigned u; } v; v.f = x;
    unsigned r = (v.u + 0x7FFFu + ((v.u >> 16) & 1u)) >> 16;
    return (u16)r;
}
__device__ __forceinline__ float bf2f(u16 b) {
    union { float f; unsigned u; } v; v.u = ((unsigned)b) << 16;
    return v.f;
}

__device__ __forceinline__ void gll16(const void* g, void* l) {
    __builtin_amdgcn_global_load_lds(
        (const __attribute__((address_space(1))) void*)g,
        (__attribute__((address_space(3))) void*)l, 16, 0, 0);
}

__global__ void cnorm_kernel(const float* __restrict__ codebook, float* __restrict__ cnorm) {
    int c = blockIdx.x * blockDim.x + threadIdx.x;
    if (c >= K) return;
    const float4* row = reinterpret_cast<const float4*>(codebook + (size_t)c * D);
    float s = 0.f;
#pragma unroll
    for (int i = 0; i < D / 4; ++i) {
        float4 v = row[i];
        s += v.x * v.x + v.y * v.y + v.z * v.z + v.w * v.w;
    }
    cnorm[c] = s;
}

// codebook fp32 -> bf16 hi/lo, chunk images of 32KB (hi 16KB + lo 16KB),
// stored pre-XOR-swizzled so global_load_lds (linear) + swizzled ds_read works.
__global__ void prep_cb(const float* __restrict__ cb, u16* __restrict__ frag) {
    int tid = blockIdx.x * blockDim.x + threadIdx.x;   // 0..32767
    int rc = tid >> 5, d4 = tid & 31;
    float4 v = reinterpret_cast<const float4*>(cb)[tid];
    u16 h0 = f2bf(v.x), h1 = f2bf(v.y), h2 = f2bf(v.z), h3 = f2bf(v.w);
    u16 l0 = f2bf(v.x - bf2f(h0)), l1 = f2bf(v.y - bf2f(h1));
    u16 l2 = f2bf(v.z - bf2f(h2)), l3 = f2bf(v.w - bf2f(h3));
    int c = rc >> 6, row = rc & 63;
    int sb = (row * 256 + d4 * 8) ^ ((row & 7) << 4);
    char* base = (char*)frag + (size_t)c * 32768;
    *reinterpret_cast<ushort4*>(base + sb) = make_ushort4(h0, h1, h2, h3);
    *reinterpret_cast<ushort4*>(base + 16384 + sb) = make_ushort4(l0, l1, l2, l3);
}

__global__ __launch_bounds__(256, 4)
void vq_main32(const float* __restrict__ z, const float* __restrict__ codebook,
               const float* __restrict__ cnorm, const u16* __restrict__ frag,
               int* __restrict__ hist, float* __restrict__ loss_accum,
               float* __restrict__ out_zq, float* __restrict__ out_idx,
               float* __restrict__ out_dist) {
    __shared__ u16 Bsh[16384];          // 32 KB: staging buffer, later reduce scratch
    __shared__ float cn_s[K];
    __shared__ float xn_s[32];
    __shared__ int bi_s[32], si_s[32], best_s[32];

    const int t = threadIdx.x;
    const int lane = t & 63;
    const int wave = t >> 6;
    const int lr = lane & 15, lg = lane >> 4;
    const int rowgrp = wave & 1, colhalf = wave >> 1;
    const int row_base = blockIdx.x * 32;

    if (t < 32) xn_s[t] = 0.f;
#pragma unroll
    for (int k = 0; k < 4; ++k) cn_s[t + k * 256] = cnorm[t + k * 256];
    __syncthreads();

    // ---- stage + convert A tile (32 rows x 128), swizzled, hi at 0 / lo at +8KB ----
    {
        const float4* zg = reinterpret_cast<const float4*>(z + (size_t)row_base * D);
#pragma unroll
        for (int k = 0; k < 4; ++k) {
            int f = t + k * 256;          // 0..1023
            int r = f >> 5, d4 = f & 31;
            float4 v = zg[f];
            u16 h0 = f2bf(v.x), h1 = f2bf(v.y), h2 = f2bf(v.z), h3 = f2bf(v.w);
            u16 l0 = f2bf(v.x - bf2f(h0)), l1 = f2bf(v.y - bf2f(h1));
            u16 l2 = f2bf(v.z - bf2f(h2)), l3 = f2bf(v.w - bf2f(h3));
            int sb = (r * 256 + d4 * 8) ^ ((r & 7) << 4);
            *reinterpret_cast<ushort4*>((char*)Bsh + sb) = make_ushort4(h0, h1, h2, h3);
            *reinterpret_cast<ushort4*>((char*)Bsh + 8192 + sb) = make_ushort4(l0, l1, l2, l3);
            atomicAdd(&xn_s[r], v.x * v.x + v.y * v.y + v.z * v.z + v.w * v.w);
        }
    }
    __syncthreads();

    // ---- hoist A fragments ----
    const int arow = rowgrp * 16 + lr;
    bf16x8 afh[4], afl[4];
#pragma unroll
    for (int kb = 0; kb < 4; ++kb) {
        int sb = (arow * 256 + kb * 64 + lg * 16) ^ ((arow & 7) << 4);
        afh[kb] = *reinterpret_cast<const bf16x8*>((char*)Bsh + sb);
        afl[kb] = *reinterpret_cast<const bf16x8*>((char*)Bsh + 8192 + sb);
    }
    float xnq[4];
#pragma unroll
    for (int q = 0; q < 4; ++q) xnq[q] = xn_s[rowgrp * 16 + lg * 4 + q];

    float v1[4], v2[4];
    int i1[4], i2[4];
#pragma unroll
    for (int q = 0; q < 4; ++q) { v1[q] = INFINITY; v2[q] = INFINITY; i1[q] = K; i2[q] = K; }

    for (int c = 0; c < 16; ++c) {
        __syncthreads();   // all waves done reading Bsh (A-frags or prev chunk)
        {
            const char* src = (const char*)frag + (size_t)c * 32768 + t * 16;
            char* dst = (char*)Bsh + t * 16;
#pragma unroll
            for (int it = 0; it < 8; ++it)
                gll16(src + it * 4096, dst + it * 4096);
        }
        __syncthreads();   // vmcnt(0) drained by barrier -> data visible

        f32x4 acc[2];
#pragma unroll
        for (int nt = 0; nt < 2; ++nt) { acc[nt][0] = 0.f; acc[nt][1] = 0.f; acc[nt][2] = 0.f; acc[nt][3] = 0.f; }

#pragma unroll
        for (int kb = 0; kb < 4; ++kb) {
#pragma unroll
            for (int nt = 0; nt < 2; ++nt) {
                int brow = colhalf * 32 + nt * 16 + lr;
                int sb = (brow * 256 + kb * 64 + lg * 16) ^ ((brow & 7) << 4);
                bf16x8 bh = *reinterpret_cast<const bf16x8*>((char*)Bsh + sb);
                bf16x8 bl = *reinterpret_cast<const bf16x8*>((char*)Bsh + 16384 + sb);
                acc[nt] = __builtin_amdgcn_mfma_f32_16x16x32_bf16(afh[kb], bh, acc[nt], 0, 0, 0);
                acc[nt] = __builtin_amdgcn_mfma_f32_16x16x32_bf16(afh[kb], bl, acc[nt], 0, 0, 0);
                acc[nt] = __builtin_amdgcn_mfma_f32_16x16x32_bf16(afl[kb], bh, acc[nt], 0, 0, 0);
            }
        }

        // epilogue: distances + stores + top-2
#pragma unroll
        for (int nt = 0; nt < 2; ++nt) {
            int col = c * 64 + colhalf * 32 + nt * 16 + lr;
            float cn = cn_s[col];
            float* orow = out_dist + (size_t)(row_base + rowgrp * 16 + lg * 4) * K + col;
#pragma unroll
            for (int q = 0; q < 4; ++q) {
                float dist = xnq[q] - 2.f * acc[nt][q] + cn;
                orow[(size_t)q * K] = dist;
                if (dist < v1[q]) { v2[q] = v1[q]; i2[q] = i1[q]; v1[q] = dist; i1[q] = col; }
                else if (dist < v2[q]) { v2[q] = dist; i2[q] = col; }
            }
        }
    }

    __syncthreads();
    // ---- cross-lane top-2 reduce via LDS scratch (transposed: reads conflict-free) ----
    float* rv1 = reinterpret_cast<float*>(Bsh);      // [32 slots][32 rows]
    float* rv2 = rv1 + 1024;
    int* ri1 = reinterpret_cast<int*>(rv2 + 1024);
    int* ri2 = ri1 + 1024;
    const int slot = colhalf * 16 + lr;
#pragma unroll
    for (int q = 0; q < 4; ++q) {
        int rr = rowgrp * 16 + lg * 4 + q;
        rv1[slot * 32 + rr] = v1[q];
        rv2[slot * 32 + rr] = v2[q];
        ri1[slot * 32 + rr] = i1[q];
        ri2[slot * 32 + rr] = i2[q];
    }
    __syncthreads();

    if (t < 32) {
        float bv = INFINITY, sv = INFINITY;
        int bi = K, si = K;
        for (int s = 0; s < 32; ++s) {
            float cv1 = rv1[s * 32 + t]; int ci1 = ri1[s * 32 + t];
            float cv2 = rv2[s * 32 + t]; int ci2 = ri2[s * 32 + t];
            if (cv1 < bv || (cv1 == bv && ci1 < bi)) { sv = bv; si = bi; bv = cv1; bi = ci1; }
            else if (cv1 < sv || (cv1 == sv && ci1 < si)) { sv = cv1; si = ci1; }
            if (cv2 < bv || (cv2 == bv && ci2 < bi)) { sv = bv; si = bi; bv = cv2; bi = ci2; }
            else if (cv2 < sv || (cv2 == sv && ci2 < si)) { sv = cv2; si = ci2; }
        }
        bi_s[t] = bi;
        si_s[t] = si;
    }
    __syncthreads();

    // ---- fp64 refinement (4 threads/row, rows 0..31) + loss ----
    float lossv = 0.f;
    if (t < 128) {
        const int rr = t >> 2, t4 = t & 3;
        const int bi = bi_s[rr], si = si_s[rr];
        const float4* zr = reinterpret_cast<const float4*>(z + (size_t)(row_base + rr) * D);
        const float4* c1 = reinterpret_cast<const float4*>(codebook + (size_t)bi * D);
        const float4* c2 = reinterpret_cast<const float4*>(codebook + (size_t)si * D);
        double d1 = 0.0, d2 = 0.0;
#pragma unroll
        for (int j = 0; j < 8; ++j) {
            float4 xv = zr[t4 * 8 + j];
            float4 a = c1[t4 * 8 + j];
            float4 b = c2[t4 * 8 + j];
            double e;
            e = (double)xv.x - (double)a.x; d1 += e * e;
            e = (double)xv.y - (double)a.y; d1 += e * e;
            e = (double)xv.z - (double)a.z; d1 += e * e;
            e = (double)xv.w - (double)a.w; d1 += e * e;
            e = (double)xv.x - (double)b.x; d2 += e * e;
            e = (double)xv.y - (double)b.y; d2 += e * e;
            e = (double)xv.z - (double)b.z; d2 += e * e;
            e = (double)xv.w - (double)b.w; d2 += e * e;
        }
        d1 += __shfl_xor(d1, 1); d1 += __shfl_xor(d1, 2);
        d2 += __shfl_xor(d2, 1); d2 += __shfl_xor(d2, 2);
        if (t4 == 0) {
            int fi = bi; double dmin = d1;
            if (d2 < d1 || (d2 == d1 && si < bi)) { fi = si; dmin = d2; }
            best_s[rr] = fi;
            out_idx[row_base + rr] = (float)fi;
            atomicAdd(&hist[fi], 1);
            lossv = (float)dmin;
        }
    }
#pragma unroll
    for (int o = 32; o > 0; o >>= 1) lossv += __shfl_down(lossv, o);
    if (lane == 0) atomicAdd(loss_accum, lossv);
    __syncthreads();

    // ---- z_q gather ----
    {
        const float4* cb4 = reinterpret_cast<const float4*>(codebook);
        float4* zq4 = reinterpret_cast<float4*>(out_zq + (size_t)row_base * D);
#pragma unroll
        for (int k = 0; k < 4; ++k) {
            int f = t + k * 256;
            int r = f >> 5, d4 = f & 31;
            zq4[f] = cb4[(size_t)best_s[r] * 32 + d4];
        }
    }
}

// ---------------- fallback (round-2 kernel) if ws too small ----------------
#define FBM 64
#define FPAD 136

__global__ __launch_bounds__(256, 2)
void vq_main_fb(const float* __restrict__ z, const float* __restrict__ codebook,
                const float* __restrict__ cnorm, int* __restrict__ hist,
                float* __restrict__ loss_accum,
                float* __restrict__ out_zq, float* __restrict__ out_idx,
                float* __restrict__ out_dist) {
    __shared__ u16 Ah[FBM][FPAD], Al[FBM][FPAD];
    __shared__ u16 Bh[FBM][FPAD], Bl[FBM][FPAD];
    __shared__ float xn_s[FBM];
    __shared__ float cn_s[K];
    __shared__ int bi_s[FBM], si_s[FBM], best_s[FBM];

    const int t = threadIdx.x;
    const int lane = t & 63;
    const int wave = t >> 6;
    const int lr = lane & 15;
    const int lg = lane >> 4;
    const int row_base = blockIdx.x * FBM;

    if (t < FBM) xn_s[t] = 0.f;
    __syncthreads();
    {
        const float4* zg = reinterpret_cast<const float4*>(z + (size_t)row_base * D);
#pragma unroll
        for (int k = 0; k < 8; ++k) {
            int f = t + k * 256;
            int r = f >> 5, d4 = f & 31;
            float4 v = zg[f];
            u16 h0 = f2bf(v.x), h1 = f2bf(v.y), h2 = f2bf(v.z), h3 = f2bf(v.w);
            u16 l0 = f2bf(v.x - bf2f(h0)), l1 = f2bf(v.y - bf2f(h1));
            u16 l2 = f2bf(v.z - bf2f(h2)), l3 = f2bf(v.w - bf2f(h3));
            *reinterpret_cast<ushort4*>(&Ah[r][d4 * 4]) = make_ushort4(h0, h1, h2, h3);
            *reinterpret_cast<ushort4*>(&Al[r][d4 * 4]) = make_ushort4(l0, l1, l2, l3);
            atomicAdd(&xn_s[r], v.x * v.x + v.y * v.y + v.z * v.z + v.w * v.w);
        }
#pragma unroll
        for (int k = 0; k < 4; ++k) cn_s[t + k * 256] = cnorm[t + k * 256];
    }
    __syncthreads();

    const int arow = wave * 16 + lr;
    bf16x8 afh[4], afl[4];
#pragma unroll
    for (int kb = 0; kb < 4; ++kb) {
        afh[kb] = *reinterpret_cast<const bf16x8*>(&Ah[arow][kb * 32 + lg * 8]);
        afl[kb] = *reinterpret_cast<const bf16x8*>(&Al[arow][kb * 32 + lg * 8]);
    }
    float xn[4];
#pragma unroll
    for (int q = 0; q < 4; ++q) xn[q] = xn_s[wave * 16 + lg * 4 + q];

    float v1[4], v2[4];
    int i1[4], i2[4];
#pragma unroll
    for (int q = 0; q < 4; ++q) { v1[q] = INFINITY; v2[q] = INFINITY; i1[q] = K; i2[q] = K; }

    for (int c = 0; c < 16; ++c) {
        __syncthreads();
        {
            const float4* cg = reinterpret_cast<const float4*>(codebook + (size_t)c * FBM * D);
#pragma unroll
            for (int k = 0; k < 8; ++k) {
                int f = t + k * 256;
                int r = f >> 5, d4 = f & 31;
                float4 v = cg[f];
                u16 h0 = f2bf(v.x), h1 = f2bf(v.y), h2 = f2bf(v.z), h3 = f2bf(v.w);
                u16 l0 = f2bf(v.x - bf2f(h0)), l1 = f2bf(v.y - bf2f(h1));
                u16 l2 = f2bf(v.z - bf2f(h2)), l3 = f2bf(v.w - bf2f(h3));
                *reinterpret_cast<ushort4*>(&Bh[r][d4 * 4]) = make_ushort4(h0, h1, h2, h3);
                *reinterpret_cast<ushort4*>(&Bl[r][d4 * 4]) = make_ushort4(l0, l1, l2, l3);
            }
        }
        __syncthreads();

        f32x4 acc[4];
#pragma unroll
        for (int nt = 0; nt < 4; ++nt) { acc[nt][0] = 0.f; acc[nt][1] = 0.f; acc[nt][2] = 0.f; acc[nt][3] = 0.f; }
#pragma unroll
        for (int kb = 0; kb < 4; ++kb) {
            bf16x8 bh[4], bl[4];
#pragma unroll
            for (int nt = 0; nt < 4; ++nt) {
                bh[nt] = *reinterpret_cast<const bf16x8*>(&Bh[nt * 16 + lr][kb * 32 + lg * 8]);
                bl[nt] = *reinterpret_cast<const bf16x8*>(&Bl[nt * 16 + lr][kb * 32 + lg * 8]);
            }
#pragma unroll
            for (int nt = 0; nt < 4; ++nt) {
                acc[nt] = __builtin_amdgcn_mfma_f32_16x16x32_bf16(afh[kb], bh[nt], acc[nt], 0, 0, 0);
                acc[nt] = __builtin_amdgcn_mfma_f32_16x16x32_bf16(afh[kb], bl[nt], acc[nt], 0, 0, 0);
                acc[nt] = __builtin_amdgcn_mfma_f32_16x16x32_bf16(afl[kb], bh[nt], acc[nt], 0, 0, 0);
            }
        }
#pragma unroll
        for (int nt = 0; nt < 4; ++nt) {
            int col = c * FBM + nt * 16 + lr;
            float cn = cn_s[col];
            float* orow = out_dist + (size_t)(row_base + wave * 16 + lg * 4) * K + col;
#pragma unroll
            for (int q = 0; q < 4; ++q) {
                float dist = xn[q] - 2.f * acc[nt][q] + cn;
                orow[(size_t)q * K] = dist;
                if (dist < v1[q]) { v2[q] = v1[q]; i2[q] = i1[q]; v1[q] = dist; i1[q] = col; }
                else if (dist < v2[q]) { v2[q] = dist; i2[q] = col; }
            }
        }
    }

    __syncthreads();
    float* rv1 = reinterpret_cast<float*>(&Bh[0][0]);
    float* rv2 = rv1 + FBM * 16;
    int* ri1 = reinterpret_cast<int*>(&Bl[0][0]);
    int* ri2 = ri1 + FBM * 16;
#pragma unroll
    for (int q = 0; q < 4; ++q) {
        int rl = wave * 16 + lg * 4 + q;
        rv1[rl * 16 + lr] = v1[q];
        rv2[rl * 16 + lr] = v2[q];
        ri1[rl * 16 + lr] = i1[q];
        ri2[rl * 16 + lr] = i2[q];
    }
    __syncthreads();

    if (t < FBM) {
        float bv = INFINITY, sv = INFINITY;
        int bi = K, si = K;
        for (int s = 0; s < 16; ++s) {
            float cv1 = rv1[t * 16 + s]; int ci1 = ri1[t * 16 + s];
            float cv2 = rv2[t * 16 + s]; int ci2 = ri2[t * 16 + s];
            if (cv1 < bv || (cv1 == bv && ci1 < bi)) { sv = bv; si = bi; bv = cv1; bi = ci1; }
            else if (cv1 < sv || (cv1 == sv && ci1 < si)) { sv = cv1; si = ci1; }
            if (cv2 < bv || (cv2 == bv && ci2 < bi)) { sv = bv; si = bi; bv = cv2; bi = ci2; }
            else if (cv2 < sv || (cv2 == sv && ci2 < si)) { sv = cv2; si = ci2; }
        }
        bi_s[t] = bi;
        si_s[t] = si;
    }
    __syncthreads();

    {
        const int rr = t >> 2, t4 = t & 3;
        const int bi = bi_s[rr], si = si_s[rr];
        const float4* zr = reinterpret_cast<const float4*>(z + (size_t)(row_base + rr) * D);
        const float4* c1 = reinterpret_cast<const float4*>(codebook + (size_t)bi * D);
        const float4* c2 = reinterpret_cast<const float4*>(codebook + (size_t)si * D);
        double d1 = 0.0, d2 = 0.0;
#pragma unroll
        for (int j = 0; j < 8; ++j) {
            float4 xv = zr[t4 * 8 + j];
            float4 a = c1[t4 * 8 + j];
            float4 b = c2[t4 * 8 + j];
            double e;
            e = (double)xv.x - (double)a.x; d1 += e * e;
            e = (double)xv.y - (double)a.y; d1 += e * e;
            e = (double)xv.z - (double)a.z; d1 += e * e;
            e = (double)xv.w - (double)a.w; d1 += e * e;
            e = (double)xv.x - (double)b.x; d2 += e * e;
            e = (double)xv.y - (double)b.y; d2 += e * e;
            e = (double)xv.z - (double)b.z; d2 += e * e;
            e = (double)xv.w - (double)b.w; d2 += e * e;
        }
        d1 += __shfl_xor(d1, 1); d1 += __shfl_xor(d1, 2);
        d2 += __shfl_xor(d2, 1); d2 += __shfl_xor(d2, 2);
        float lossv = 0.f;
        if (t4 == 0) {
            int fi = bi; double dmin = d1;
            if (d2 < d1 || (d2 == d1 && si < bi)) { fi = si; dmin = d2; }
            best_s[rr] = fi;
            out_idx[row_base + rr] = (float)fi;
            atomicAdd(&hist[fi], 1);
            lossv = (float)dmin;
        }
#pragma unroll
        for (int o = 32; o > 0; o >>= 1) lossv += __shfl_down(lossv, o);
        if (lane == 0) atomicAdd(loss_accum, lossv);
    }
    __syncthreads();
    {
        const float4* cb4 = reinterpret_cast<const float4*>(codebook);
        float4* zq4 = reinterpret_cast<float4*>(out_zq + (size_t)row_base * D);
#pragma unroll
        for (int k = 0; k < 8; ++k) {
            int f = t + k * 256;
            int r = f >> 5, d4 = f & 31;
            zq4[f] = cb4[(size_t)best_s[r] * 32 + d4];
        }
    }
}

__global__ void vq_finalize(const int* __restrict__ hist, const float* __restrict__ loss_accum,
                            float* __restrict__ out_scalars, int M) {
    __shared__ float red[256];
    int t = threadIdx.x;
    float s = 0.f;
    float invM = 1.0f / (float)M;
#pragma unroll
    for (int k = 0; k < K / 256; ++k) {
        float p = (float)hist[t + k * 256] * invM;
        s += p * logf(p + 1e-10f);
    }
    red[t] = s;
    __syncthreads();
    for (int off = 128; off > 0; off >>= 1) {
        if (t < off) red[t] += red[t + off];
        __syncthreads();
    }
    if (t == 0) {
        float loss = loss_accum[0] / ((float)M * (float)D);
        out_scalars[0] = 0.25f * loss;
        out_scalars[1] = loss;
        out_scalars[2] = expf(-red[0]);
    }
}

extern "C" void kernel_launch(void* const* d_in, const int* in_sizes, int n_in,
                              void* d_out, int out_size, void* d_ws, size_t ws_size,
                              hipStream_t stream) {
    const float* z = (const float*)d_in[0];
    const float* codebook = (const float*)d_in[1];
    int M = in_sizes[0] / D;   // 32768

    float* out = (float*)d_out;
    float* out_zq = out;                    // M*D
    float* out_idx = out + (size_t)M * D;   // M
    float* out_scalars = out_idx + M;       // 3
    float* out_dist = out_scalars + 3;      // M*K

    int* hist = (int*)d_ws;
    float* loss_accum = (float*)((char*)d_ws + 4096);
    float* cnorm = (float*)((char*)d_ws + 8192);
    u16* frag = (u16*)((char*)d_ws + 16384);

    hipMemsetAsync(d_ws, 0, 8192, stream);
    cnorm_kernel<<<K / 256, 256, 0, stream>>>(codebook, cnorm);
    if (ws_size >= (size_t)(16384 + 524288)) {
        prep_cb<<<128, 256, 0, stream>>>(codebook, frag);
        vq_main32<<<M / 32, 256, 0, stream>>>(z, codebook, cnorm, frag, hist, loss_accum,
                                              out_zq, out_idx, out_dist);
    } else {
        vq_main_fb<<<M / 64, 256, 0, stream>>>(z, codebook, cnorm, hist, loss_accum,
                                               out_zq, out_idx, out_dist);
    }
    vq_finalize<<<1, 256, 0, stream>>>(hist, loss_accum, out_scalars, M);
}

// Round 4
// 114.398 us; speedup vs baseline: 1.1351x; 1.1351x over previous
//
#include <hip/hip_runtime.h>
#include <math.h>

#define D 128
#define K 1024
#define BM 32          // z-rows per block
#define BN 32          // codes per chunk
#define NCH (K / BN)   // 32 chunks
#define CHB 16384      // bytes per chunk image (hi 8K + lo 8K)

typedef __attribute__((ext_vector_type(8))) short bf16x8;
typedef __attribute__((ext_vector_type(4))) float f32x4;
typedef unsigned short u16;

// ws layout: [0,4096) hist | [4096,4100) loss | [8192,12288) cnorm | [16384,+512K) frag image

__device__ __forceinline__ u16 f2bf(float x) {
    union { float f; unsigned u; } v; v.f = x;
    unsigned r = (v.u + 0x7FFFu + ((v.u >> 16) & 1u)) >> 16;
    return (u16)r;
}
__device__ __forceinline__ float bf2f(u16 b) {
    union { float f; unsigned u; } v; v.u = ((unsigned)b) << 16;
    return v.f;
}
__device__ __forceinline__ void gll16(const void* g, void* l) {
    __builtin_amdgcn_global_load_lds(
        (const __attribute__((address_space(1))) void*)g,
        (__attribute__((address_space(3))) void*)l, 16, 0, 0);
}

// codebook fp32 -> bf16 hi/lo chunk images (32 codes each), pre-swizzled; fused cnorm.
__global__ void prep_cb(const float* __restrict__ cb, u16* __restrict__ frag,
                        float* __restrict__ cnorm) {
    int tid = blockIdx.x * blockDim.x + threadIdx.x;   // 0..32767, one float4 per thread
    int code = tid >> 5, d4 = tid & 31;
    float4 v = reinterpret_cast<const float4*>(cb)[tid];
    u16 h0 = f2bf(v.x), h1 = f2bf(v.y), h2 = f2bf(v.z), h3 = f2bf(v.w);
    u16 l0 = f2bf(v.x - bf2f(h0)), l1 = f2bf(v.y - bf2f(h1));
    u16 l2 = f2bf(v.z - bf2f(h2)), l3 = f2bf(v.w - bf2f(h3));
    int c = code >> 5, row = code & 31;
    int sb = (row * 256 + d4 * 8) ^ ((row & 7) << 4);
    char* base = (char*)frag + (size_t)c * CHB;
    *reinterpret_cast<ushort4*>(base + sb) = make_ushort4(h0, h1, h2, h3);
    *reinterpret_cast<ushort4*>(base + 8192 + sb) = make_ushort4(l0, l1, l2, l3);
    // fused cnorm: reduce sumsq across the 32 lanes of this code
    float s = v.x * v.x + v.y * v.y + v.z * v.z + v.w * v.w;
#pragma unroll
    for (int m = 1; m <= 16; m <<= 1) s += __shfl_xor(s, m);
    if (d4 == 0) cnorm[code] = s;
}

__global__ __launch_bounds__(256, 4)
void vq_main(const float* __restrict__ z, const float* __restrict__ codebook,
             const float* __restrict__ cnorm, const u16* __restrict__ frag,
             int* __restrict__ hist, float* __restrict__ loss_accum,
             float* __restrict__ out_zq, float* __restrict__ out_idx,
             float* __restrict__ out_dist) {
    __shared__ u16 Bsh[2][8192];       // 2 x 16 KB double buffer (also A-stage, also scratch)
    __shared__ float cn_s[K];
    __shared__ float xn_s[BM];
    __shared__ int bi_s[BM], si_s[BM], best_s[BM];

    const int t = threadIdx.x;
    const int lane = t & 63;
    const int wave = t >> 6;
    const int lr = lane & 15, lg = lane >> 4;
    const int rowgrp = wave & 1, colhalf = wave >> 1;
    const int row_base = blockIdx.x * BM;

    if (t < BM) xn_s[t] = 0.f;
#pragma unroll
    for (int k = 0; k < 4; ++k) cn_s[t + k * 256] = cnorm[t + k * 256];
    __syncthreads();

    // ---- stage + convert A tile (32 rows x 128) into Bsh[0], swizzled hi/lo ----
    {
        const float4* zg = reinterpret_cast<const float4*>(z + (size_t)row_base * D);
#pragma unroll
        for (int k = 0; k < 4; ++k) {
            int f = t + k * 256;
            int r = f >> 5, d4 = f & 31;
            float4 v = zg[f];
            u16 h0 = f2bf(v.x), h1 = f2bf(v.y), h2 = f2bf(v.z), h3 = f2bf(v.w);
            u16 l0 = f2bf(v.x - bf2f(h0)), l1 = f2bf(v.y - bf2f(h1));
            u16 l2 = f2bf(v.z - bf2f(h2)), l3 = f2bf(v.w - bf2f(h3));
            int sb = (r * 256 + d4 * 8) ^ ((r & 7) << 4);
            *reinterpret_cast<ushort4*>((char*)Bsh + sb) = make_ushort4(h0, h1, h2, h3);
            *reinterpret_cast<ushort4*>((char*)Bsh + 8192 + sb) = make_ushort4(l0, l1, l2, l3);
            atomicAdd(&xn_s[r], v.x * v.x + v.y * v.y + v.z * v.z + v.w * v.w);
        }
    }
    __syncthreads();

    // ---- hoist z fragments (B-operand now) + xn scalar ----
    const int arow = rowgrp * 16 + lr;
    bf16x8 zh[4], zl[4];
#pragma unroll
    for (int kb = 0; kb < 4; ++kb) {
        int sb = (arow * 256 + kb * 64 + lg * 16) ^ ((arow & 7) << 4);
        zh[kb] = *reinterpret_cast<const bf16x8*>((char*)Bsh + sb);
        zl[kb] = *reinterpret_cast<const bf16x8*>((char*)Bsh + 8192 + sb);
    }
    const float xn = xn_s[arow];

    // ---- prefetch chunk 0 into Bsh[1] ----
    const char* fsrc = (const char*)frag + t * 16;
    {
        char* dst = (char*)Bsh + 16384 + t * 16;
#pragma unroll
        for (int it = 0; it < 4; ++it) gll16(fsrc + it * 4096, dst + it * 4096);
    }
    __syncthreads();   // drains vmcnt(0): chunk0 staged; all hoist reads done

    float v1 = INFINITY, v2 = INFINITY;
    int i1 = K, i2 = K;
    int cur = 1;
    const int myrow = row_base + rowgrp * 16 + lr;
    float* orow = out_dist + (size_t)myrow * K + colhalf * 16 + lg * 4;
    const int crow = colhalf * 16 + lr;

    for (int c = 0; c < NCH; ++c) {
        if (c < NCH - 1) {   // issue next-chunk staging (overlaps with compute below)
            const char* src = fsrc + (size_t)(c + 1) * CHB;
            char* dst = (char*)Bsh + (cur ^ 1) * 16384 + t * 16;
#pragma unroll
            for (int it = 0; it < 4; ++it) gll16(src + it * 4096, dst + it * 4096);
        }

        const char* bb = (const char*)Bsh + cur * 16384;
        f32x4 acc = {0.f, 0.f, 0.f, 0.f};
#pragma unroll
        for (int kb = 0; kb < 4; ++kb) {
            int sb = (crow * 256 + kb * 64 + lg * 16) ^ ((crow & 7) << 4);
            bf16x8 ch = *reinterpret_cast<const bf16x8*>(bb + sb);
            bf16x8 cl = *reinterpret_cast<const bf16x8*>(bb + 8192 + sb);
            acc = __builtin_amdgcn_mfma_f32_16x16x32_bf16(ch, zh[kb], acc, 0, 0, 0);
            acc = __builtin_amdgcn_mfma_f32_16x16x32_bf16(ch, zl[kb], acc, 0, 0, 0);
            acc = __builtin_amdgcn_mfma_f32_16x16x32_bf16(cl, zh[kb], acc, 0, 0, 0);
        }

        // epilogue: 4 consecutive-code distances for my z-row -> float4 store + top-2
        const int cbase = c * BN + colhalf * 16 + lg * 4;
        float4 cn4 = *reinterpret_cast<const float4*>(&cn_s[cbase]);
        float d0 = fmaf(-2.f, acc[0], xn + cn4.x);
        float d1 = fmaf(-2.f, acc[1], xn + cn4.y);
        float d2 = fmaf(-2.f, acc[2], xn + cn4.z);
        float d3 = fmaf(-2.f, acc[3], xn + cn4.w);
        if (d0 < v1) { v2 = v1; i2 = i1; v1 = d0; i1 = cbase; }
        else if (d0 < v2) { v2 = d0; i2 = cbase; }
        if (d1 < v1) { v2 = v1; i2 = i1; v1 = d1; i1 = cbase + 1; }
        else if (d1 < v2) { v2 = d1; i2 = cbase + 1; }
        if (d2 < v1) { v2 = v1; i2 = i1; v1 = d2; i1 = cbase + 2; }
        else if (d2 < v2) { v2 = d2; i2 = cbase + 2; }
        if (d3 < v1) { v2 = v1; i2 = i1; v1 = d3; i1 = cbase + 3; }
        else if (d3 < v2) { v2 = d3; i2 = cbase + 3; }
        *reinterpret_cast<float4*>(orow + (size_t)c * BN) = make_float4(d0, d1, d2, d3);

        __syncthreads();   // next-chunk loads drained; buffer swap safe
        cur ^= 1;
    }

    // ---- cross-lane top-2 reduce: 8 slots per row, scratch overlays Bsh[0] ----
    float* rv1 = reinterpret_cast<float*>(Bsh);          // [8 slots][32 rows]
    float* rv2 = rv1 + 256;
    int* ri1 = reinterpret_cast<int*>(rv2 + 256);
    int* ri2 = ri1 + 256;
    {
        const int slot = colhalf * 4 + lg;
        const int rr = rowgrp * 16 + lr;
        rv1[slot * 32 + rr] = v1;
        rv2[slot * 32 + rr] = v2;
        ri1[slot * 32 + rr] = i1;
        ri2[slot * 32 + rr] = i2;
    }
    __syncthreads();

    if (t < BM) {
        float bv = INFINITY, sv = INFINITY;
        int bi = K, si = K;
        for (int s = 0; s < 8; ++s) {
            float cv1 = rv1[s * 32 + t]; int ci1 = ri1[s * 32 + t];
            float cv2 = rv2[s * 32 + t]; int ci2 = ri2[s * 32 + t];
            if (cv1 < bv || (cv1 == bv && ci1 < bi)) { sv = bv; si = bi; bv = cv1; bi = ci1; }
            else if (cv1 < sv || (cv1 == sv && ci1 < si)) { sv = cv1; si = ci1; }
            if (cv2 < bv || (cv2 == bv && ci2 < bi)) { sv = bv; si = bi; bv = cv2; bi = ci2; }
            else if (cv2 < sv || (cv2 == sv && ci2 < si)) { sv = cv2; si = ci2; }
        }
        bi_s[t] = bi;
        si_s[t] = si;
    }
    __syncthreads();

    // ---- fp64 refinement (4 threads/row) + loss (= ||q-z||^2) ----
    float lossv = 0.f;
    if (t < 128) {
        const int rr = t >> 2, t4 = t & 3;
        const int bi = bi_s[rr], si = si_s[rr];
        const float4* zr = reinterpret_cast<const float4*>(z + (size_t)(row_base + rr) * D);
        const float4* c1 = reinterpret_cast<const float4*>(codebook + (size_t)bi * D);
        const float4* c2 = reinterpret_cast<const float4*>(codebook + (size_t)si * D);
        double dd1 = 0.0, dd2 = 0.0;
#pragma unroll
        for (int j = 0; j < 8; ++j) {
            float4 xv = zr[t4 * 8 + j];
            float4 a = c1[t4 * 8 + j];
            float4 b = c2[t4 * 8 + j];
            double e;
            e = (double)xv.x - (double)a.x; dd1 += e * e;
            e = (double)xv.y - (double)a.y; dd1 += e * e;
            e = (double)xv.z - (double)a.z; dd1 += e * e;
            e = (double)xv.w - (double)a.w; dd1 += e * e;
            e = (double)xv.x - (double)b.x; dd2 += e * e;
            e = (double)xv.y - (double)b.y; dd2 += e * e;
            e = (double)xv.z - (double)b.z; dd2 += e * e;
            e = (double)xv.w - (double)b.w; dd2 += e * e;
        }
        dd1 += __shfl_xor(dd1, 1); dd1 += __shfl_xor(dd1, 2);
        dd2 += __shfl_xor(dd2, 1); dd2 += __shfl_xor(dd2, 2);
        if (t4 == 0) {
            int fi = bi; double dmin = dd1;
            if (dd2 < dd1 || (dd2 == dd1 && si < bi)) { fi = si; dmin = dd2; }
            best_s[rr] = fi;
            out_idx[row_base + rr] = (float)fi;
            atomicAdd(&hist[fi], 1);
            lossv = (float)dmin;
        }
    }
#pragma unroll
    for (int o = 32; o > 0; o >>= 1) lossv += __shfl_down(lossv, o);
    if (lane == 0) atomicAdd(loss_accum, lossv);
    __syncthreads();

    // ---- z_q gather ----
    {
        const float4* cb4 = reinterpret_cast<const float4*>(codebook);
        float4* zq4 = reinterpret_cast<float4*>(out_zq + (size_t)row_base * D);
#pragma unroll
        for (int k = 0; k < 4; ++k) {
            int f = t + k * 256;
            int r = f >> 5, d4 = f & 31;
            zq4[f] = cb4[(size_t)best_s[r] * 32 + d4];
        }
    }
}

__global__ void vq_finalize(const int* __restrict__ hist, const float* __restrict__ loss_accum,
                            float* __restrict__ out_scalars, int M) {
    __shared__ float red[256];
    int t = threadIdx.x;
    float s = 0.f;
    float invM = 1.0f / (float)M;
#pragma unroll
    for (int k = 0; k < K / 256; ++k) {
        float p = (float)hist[t + k * 256] * invM;
        s += p * logf(p + 1e-10f);
    }
    red[t] = s;
    __syncthreads();
    for (int off = 128; off > 0; off >>= 1) {
        if (t < off) red[t] += red[t + off];
        __syncthreads();
    }
    if (t == 0) {
        float loss = loss_accum[0] / ((float)M * (float)D);
        out_scalars[0] = 0.25f * loss;
        out_scalars[1] = loss;
        out_scalars[2] = expf(-red[0]);
    }
}

extern "C" void kernel_launch(void* const* d_in, const int* in_sizes, int n_in,
                              void* d_out, int out_size, void* d_ws, size_t ws_size,
                              hipStream_t stream) {
    const float* z = (const float*)d_in[0];
    const float* codebook = (const float*)d_in[1];
    int M = in_sizes[0] / D;   // 32768

    float* out = (float*)d_out;
    float* out_zq = out;                    // M*D
    float* out_idx = out + (size_t)M * D;   // M
    float* out_scalars = out_idx + M;       // 3
    float* out_dist = out_scalars + 3;      // M*K

    int* hist = (int*)d_ws;
    float* loss_accum = (float*)((char*)d_ws + 4096);
    float* cnorm = (float*)((char*)d_ws + 8192);
    u16* frag = (u16*)((char*)d_ws + 16384);

    hipMemsetAsync(d_ws, 0, 8192, stream);
    prep_cb<<<(K * D / 4) / 256, 256, 0, stream>>>(codebook, frag, cnorm);
    vq_main<<<M / BM, 256, 0, stream>>>(z, codebook, cnorm, frag, hist, loss_accum,
                                        out_zq, out_idx, out_dist);
    vq_finalize<<<1, 256, 0, stream>>>(hist, loss_accum, out_scalars, M);
}